// Round 5
// baseline (443.937 us; speedup 1.0000x reference)
//
#include <hip/hip_runtime.h>
#include <cstdint>

// B=2, Q=512, K=512, T=256 (fp32 in/out).
// R12: R11 (8 waves x 64q x 32u, shfl stats, lg/acc pinned, rcp) with the
// k-grid split 16->32 (16 k per block) so 2 blocks co-reside per CU
// (4 waves/SIMD) and cross-block co-scheduling fills barrier stalls.
//   p = x*exp(x); M = max_q x, S = sum_q |p|; acc += p * g,
//   g = vproj*e^-M / (S*e^-M + 1).

typedef short bf16x8 __attribute__((ext_vector_type(8)));   // 8 bf16 = 4 VGPR
typedef float f32x4  __attribute__((ext_vector_type(4)));   // MFMA C/D frag

__device__ inline float bf2f(short s) {
  return __uint_as_float(((unsigned)(unsigned short)s) << 16);
}
// f32 pair -> packed bf16 (round-half-up), low short = lo
__device__ inline unsigned packrn(float lo, float hi) {
  return __builtin_amdgcn_perm(__float_as_uint(hi) + 0x8000u,
                               __float_as_uint(lo) + 0x8000u, 0x07060302u);
}
// monotone (unsigned) encoding of f32 for atomic max; 0 == "-infinity" sentinel
__device__ inline unsigned encM(float f) {
  unsigned k = (unsigned)__float_as_int(f);
  return (k & 0x80000000u) ? ~k : (k | 0x80000000u);
}
__device__ inline float decM(unsigned k) {
  int i = (k & 0x80000000u) ? (int)(k ^ 0x80000000u) : (int)~k;
  return __int_as_float(i);
}

#define FMA16()                                                                 \
  c[0][0] += a.x*w.x; c[0][1] += a.x*w.y; c[0][2] += a.x*w.z; c[0][3] += a.x*w.w; \
  c[1][0] += a.y*w.x; c[1][1] += a.y*w.y; c[1][2] += a.y*w.z; c[1][3] += a.y*w.w; \
  c[2][0] += a.z*w.x; c[2][1] += a.z*w.y; c[2][2] += a.z*w.z; c[2][3] += a.z*w.w; \
  c[3][0] += a.w*w.x; c[3][1] += a.w*w.y; c[3][2] += a.w*w.z; c[3][3] += a.w*w.w;

// GEMM body, W row-major (transposed through LDS on load). 64x64 tile, 256 thr.
#define GEMM_BODY_RM(X, W)                                                      \
  __shared__ __align__(16) float As[16][68];                                    \
  __shared__ __align__(16) float Ws[16][68];                                    \
  const int tid = threadIdx.x;                                                  \
  const int tx4 = (tid & 15) * 4;                                               \
  const int ty4 = (tid >> 4) * 4;                                               \
  const int m0 = blockIdx.x * 64, u0 = blockIdx.y * 64;                         \
  const int lmi = tid >> 2, lc4 = (tid & 3) * 4;                                \
  float c[4][4] = {};                                                           \
  _Pragma("unroll 1")                                                           \
  for (int t0 = 0; t0 < 256; t0 += 16) {                                        \
    const float4 xa = *(const float4*)&(X)[(size_t)(m0 + lmi) * 256 + t0 + lc4];\
    const float4 wb = *(const float4*)&(W)[(size_t)(u0 + lmi) * 256 + t0 + lc4];\
    __syncthreads();                                                            \
    As[lc4 + 0][lmi] = xa.x; As[lc4 + 1][lmi] = xa.y;                           \
    As[lc4 + 2][lmi] = xa.z; As[lc4 + 3][lmi] = xa.w;                           \
    Ws[lc4 + 0][lmi] = wb.x; Ws[lc4 + 1][lmi] = wb.y;                           \
    Ws[lc4 + 2][lmi] = wb.z; Ws[lc4 + 3][lmi] = wb.w;                           \
    __syncthreads();                                                            \
    _Pragma("unroll")                                                           \
    for (int t = 0; t < 16; ++t) {                                              \
      const float4 a = *(const float4*)&As[t][ty4];                             \
      const float4 w = *(const float4*)&Ws[t][tx4];                             \
      FMA16();                                                                  \
    }                                                                           \
  }

// Projections + aux. z=0 key->kproj(f32), z=1 value->vproj(f32),
// z=2 query->qpF (bf16 A-frag-major), z=3: WalF build + vsum zero.
__global__ __launch_bounds__(256) void proj3(
    const float* __restrict__ key, const float* __restrict__ value,
    const float* __restrict__ query, const float* __restrict__ Wk,
    const float* __restrict__ Wq, const float* __restrict__ Wva,
    const float* __restrict__ Wal, float* __restrict__ kproj,
    float* __restrict__ vproj, short* __restrict__ qpF,
    short* __restrict__ WalF, float* __restrict__ vsum)
{
  const int z = blockIdx.z;
  if (z == 3) {
    const int p = blockIdx.x * 4 + blockIdx.y;    // 0..63
    const int t256 = threadIdx.x;
    // WalF: frag-major bf16 copy of Wal; 1024 shorts per block
#pragma unroll
    for (int e = 0; e < 4; ++e) {
      const int d = p * 1024 + t256 * 4 + e;
      const int j = d & 7, uu = (d >> 3) & 31, c8g = d >> 8;
      const int ucx = c8g >> 5, cc = c8g & 31;
      const float v = Wal[(ucx * 32 + uu) * 256 + cc * 8 + j];
      WalF[d] = (short)packrn(v, v);
    }
    // vsum zero: 4096 floats per block
    float4* vz = (float4*)(vsum + p * 4096);
#pragma unroll
    for (int e = 0; e < 4; ++e) vz[t256 * 4 + e] = make_float4(0.f, 0.f, 0.f, 0.f);
    return;
  }
  const float* X = (z == 0) ? key : (z == 1) ? value : query;
  const float* W = (z == 0) ? Wk  : (z == 1) ? Wva   : Wq;
  GEMM_BODY_RM(X, W);
  if (z == 2) {
    const int tbase = u0 + tx4;               // t coordinate
    const int ks = tbase >> 5, l4f = (tbase & 31) >> 3, j0 = tbase & 7;
#pragma unroll
    for (int i = 0; i < 4; ++i) {
      const int m = m0 + ty4 + i;             // global row = b*512 + q
      const int bb = m >> 9, q = m & 511;
      const int g = q >> 4, l15q = q & 15;
      const size_t idx = ((size_t)(((bb * 32 + g) * 8 + ks) * 64) + l4f * 16 + l15q) * 8 + j0;
      uint2 s; s.x = packrn(c[i][0], c[i][1]); s.y = packrn(c[i][2], c[i][3]);
      *(uint2*)&qpF[idx] = s;
    }
  } else {
    float* C = (z == 0) ? kproj : vproj;
#pragma unroll
    for (int i = 0; i < 4; ++i)
      *(float4*)&C[(size_t)(m0 + ty4 + i) * 256 + u0 + tx4] =
          make_float4(c[i][0], c[i][1], c[i][2], c[i][3]);
  }
}

// Final projection: out = vsum x Wvo^T (Wvo row-major).
__global__ __launch_bounds__(256) void gemm_out(
    const float* __restrict__ X, const float* __restrict__ W, float* __restrict__ out)
{
  GEMM_BODY_RM(X, W);
#pragma unroll
  for (int i = 0; i < 4; ++i)
    *(float4*)&out[(size_t)(m0 + ty4 + i) * 256 + u0 + tx4] =
        make_float4(c[i][0], c[i][1], c[i][2], c[i][3]);
}

union Frag { bf16x8 v; unsigned u[4]; };

// ---------------------------------------------------------------------------
// kernelC: grid (32 kt, 8 uc, 2 b) = 512 blocks -> 2 blocks/CU, 4 waves/SIMD.
// 512 thr = 8 waves; wave w: q in [w*64, w*64+64), full 32-u chunk; block
// covers 16 k. qa (64q x 256t bf16 = 128 VGPR) pinned. Per k (ONE barrier):
// MFMA from W2F[k&1]; build W2F[(k+1)&1]; shfl stats + l4==0 LDS atomics
// (slot k%3); barrier; per-lane g (rcp); apply; reset slot (k+2)%3.
// lg/acc pinned to "v" class to prevent AGPR shuttling.
// ---------------------------------------------------------------------------
__global__ __launch_bounds__(512, 4) void kernelC(
    const short* __restrict__ qpF, const float* __restrict__ kproj,
    const float* __restrict__ vproj, const short* __restrict__ WalF,
    float* __restrict__ vsum)
{
  __shared__ __align__(16) short W2F[2][8192];  // 2 x 16 KB, [c8][u][8]
  __shared__ float vpS[16 * 33];                // vproj tile [kk][u], padded
  __shared__ unsigned statM[96];                // 3 slots x 32 u (encoded max)
  __shared__ float statS[96];                   // 3 slots x 32 u

  const int kt = blockIdx.x, uc = blockIdx.y, b = blockIdx.z;
  const int u0 = uc * 32, k0 = kt * 16;
  const int tid = threadIdx.x;
  const int lane = tid & 63, w = tid >> 6;      // w in [0,8)
  const int l15 = lane & 15, l4 = lane >> 4;
  const int uu = tid & 31, c8 = tid >> 5;       // build mapping: c8 and c8+16

  if (tid < 96) { statM[tid] = 0u; statS[tid] = 0.f; }
  // vproj tile: 16 kk x 32 u, one float per thread (coalesced)
  vpS[(tid >> 5) * 33 + uu] =
      vproj[(size_t)(b * 512 + k0 + (tid >> 5)) * 256 + u0 + uu];

  // k-invariant Wal build octets (f32-expanded, 16 VGPR)
  float wl0[8], wl1[8];
  {
    const bf16x8 w0 = *(const bf16x8*)&WalF[((size_t)(uc * 32 + c8) * 32 + uu) * 8];
    const bf16x8 w1 = *(const bf16x8*)&WalF[((size_t)(uc * 32 + c8 + 16) * 32 + uu) * 8];
#pragma unroll
    for (int j = 0; j < 8; ++j) { wl0[j] = bf2f(w0[j]); wl1[j] = bf2f(w1[j]); }
  }

  // persistent A-fragments (128 VGPR), pinned against rematerialization
  const short* qbase = qpF + (size_t)b * 131072;
  Frag qa[4][8];
#pragma unroll
  for (int qg = 0; qg < 4; ++qg)
#pragma unroll
    for (int ks = 0; ks < 8; ++ks) {
      qa[qg][ks].v = *(const bf16x8*)&qbase[(((size_t)(w * 4 + qg) * 8 + ks) * 64 + lane) * 8];
      asm volatile("" : "+v"(qa[qg][ks].u[0]), "+v"(qa[qg][ks].u[1]),
                        "+v"(qa[qg][ks].u[2]), "+v"(qa[qg][ks].u[3]));
    }

  // per-thread constant addresses (hoisted once)
  const int fb = (l4 * 32 + l15) * 8;                               // frag base
  const float* kq = &kproj[(long)(b * 512 + k0) * 256 + c8 * 8];    // kp base

  // prologue: build W2F[0] for k = k0
  {
    const f32x4 a0 = *(const f32x4*)(kq);
    const f32x4 a1 = *(const f32x4*)(kq + 4);
    const f32x4 b0 = *(const f32x4*)(kq + 128);
    const f32x4 b1 = *(const f32x4*)(kq + 132);
    uint4 st;
    st.x = packrn(wl0[0] * a0[0], wl0[1] * a0[1]);
    st.y = packrn(wl0[2] * a0[2], wl0[3] * a0[3]);
    st.z = packrn(wl0[4] * a1[0], wl0[5] * a1[1]);
    st.w = packrn(wl0[6] * a1[2], wl0[7] * a1[3]);
    *(uint4*)&W2F[0][(c8 * 32 + uu) * 8] = st;
    st.x = packrn(wl1[0] * b0[0], wl1[1] * b0[1]);
    st.y = packrn(wl1[2] * b0[2], wl1[3] * b0[3]);
    st.z = packrn(wl1[4] * b1[0], wl1[5] * b1[1]);
    st.w = packrn(wl1[6] * b1[2], wl1[7] * b1[3]);
    *(uint4*)&W2F[0][((c8 + 16) * 32 + uu) * 8] = st;
  }
  __syncthreads();

  const f32x4 z4 = {0.f, 0.f, 0.f, 0.f};
  f32x4 acc[4][2] = {z4, z4, z4, z4, z4, z4, z4, z4};

#pragma unroll 1
  for (int kk = 0; kk < 16; ++kk) {
    const int cs = kk & 1, ss = kk % 3;

    // issue next k's kp loads early (hidden under MFMA)
    f32x4 a0, a1, b0, b1;
    if (kk < 15) {
      const float* kn = kq + (size_t)(kk + 1) * 256;
      a0 = *(const f32x4*)(kn);
      a1 = *(const f32x4*)(kn + 4);
      b0 = *(const f32x4*)(kn + 128);
      b1 = *(const f32x4*)(kn + 132);
    }

    f32x4 lg[4][2] = {z4, z4, z4, z4, z4, z4, z4, z4};
#pragma unroll
    for (int ks = 0; ks < 8; ++ks) {
      const bf16x8 f0 = *(const bf16x8*)&W2F[cs][fb + ks * 1024];
      const bf16x8 f1 = *(const bf16x8*)&W2F[cs][fb + ks * 1024 + 128];
#pragma unroll
      for (int qg = 0; qg < 4; ++qg) {
        lg[qg][0] = __builtin_amdgcn_mfma_f32_16x16x32_bf16(qa[qg][ks].v, f0, lg[qg][0], 0, 0, 0);
        lg[qg][1] = __builtin_amdgcn_mfma_f32_16x16x32_bf16(qa[qg][ks].v, f1, lg[qg][1], 0, 0, 0);
      }
    }
    // pin MFMA results into arch VGPRs (prevent AGPR residency -> shuttles)
#pragma unroll
    for (int qg = 0; qg < 4; ++qg)
      asm volatile("" : "+v"(lg[qg][0]), "+v"(lg[qg][1]));

    // build next slot (write-after-read safe: slot read last at kk-1, barrier between)
    if (kk < 15) {
      uint4 st;
      st.x = packrn(wl0[0] * a0[0], wl0[1] * a0[1]);
      st.y = packrn(wl0[2] * a0[2], wl0[3] * a0[3]);
      st.z = packrn(wl0[4] * a1[0], wl0[5] * a1[1]);
      st.w = packrn(wl0[6] * a1[2], wl0[7] * a1[3]);
      *(uint4*)&W2F[cs ^ 1][(c8 * 32 + uu) * 8] = st;
      st.x = packrn(wl1[0] * b0[0], wl1[1] * b0[1]);
      st.y = packrn(wl1[2] * b0[2], wl1[3] * b0[3]);
      st.z = packrn(wl1[4] * b1[0], wl1[5] * b1[1]);
      st.w = packrn(wl1[6] * b1[2], wl1[7] * b1[3]);
      *(uint4*)&W2F[cs ^ 1][((c8 + 16) * 32 + uu) * 8] = st;
    }

    // stats: M = max x (tree), p = x*exp(x), S = sum|p|; shfl reduce across
    // the 4 lane-groups, then one atomic per u from l4==0 lanes.
    float Mv[2], Sv[2];
#pragma unroll
    for (int ug = 0; ug < 2; ++ug) {
      const float m0q = fmaxf(fmaxf(lg[0][ug][0], lg[0][ug][1]), fmaxf(lg[0][ug][2], lg[0][ug][3]));
      const float m1q = fmaxf(fmaxf(lg[1][ug][0], lg[1][ug][1]), fmaxf(lg[1][ug][2], lg[1][ug][3]));
      const float m2q = fmaxf(fmaxf(lg[2][ug][0], lg[2][ug][1]), fmaxf(lg[2][ug][2], lg[2][ug][3]));
      const float m3q = fmaxf(fmaxf(lg[3][ug][0], lg[3][ug][1]), fmaxf(lg[3][ug][2], lg[3][ug][3]));
      float m = fmaxf(fmaxf(m0q, m1q), fmaxf(m2q, m3q));
      float sq[4];
#pragma unroll
      for (int qg = 0; qg < 4; ++qg) {
        float p0 = lg[qg][ug][0] * __expf(lg[qg][ug][0]);
        float p1 = lg[qg][ug][1] * __expf(lg[qg][ug][1]);
        float p2 = lg[qg][ug][2] * __expf(lg[qg][ug][2]);
        float p3 = lg[qg][ug][3] * __expf(lg[qg][ug][3]);
        lg[qg][ug][0] = p0; lg[qg][ug][1] = p1;
        lg[qg][ug][2] = p2; lg[qg][ug][3] = p3;
        sq[qg] = (fabsf(p0) + fabsf(p1)) + (fabsf(p2) + fabsf(p3));
      }
      float s = (sq[0] + sq[1]) + (sq[2] + sq[3]);
      m = fmaxf(m, __shfl_xor(m, 16));
      m = fmaxf(m, __shfl_xor(m, 32));
      s += __shfl_xor(s, 16);
      s += __shfl_xor(s, 32);
      Mv[ug] = m; Sv[ug] = s;
    }
    if (l4 == 0) {
      atomicMax(&statM[ss * 32 + l15],      encM(Mv[0]));
      atomicMax(&statM[ss * 32 + 16 + l15], encM(Mv[1]));
      atomicAdd(&statS[ss * 32 + l15],      Sv[0]);
      atomicAdd(&statS[ss * 32 + 16 + l15], Sv[1]);
    }
    __syncthreads();

    // per-lane g + apply (rcp: err ~1e-7, proven within tolerance)
#pragma unroll
    for (int ug = 0; ug < 2; ++ug) {
      const int ui = ug * 16 + l15;
      const float M = decM(statM[ss * 32 + ui]);
      const float S = statS[ss * 32 + ui];
      const float em = __expf(-M);
      const float g = vpS[kk * 33 + ui] * em * __builtin_amdgcn_rcpf(fmaf(S, em, 1.0f));
#pragma unroll
      for (int qg = 0; qg < 4; ++qg)
#pragma unroll
        for (int i = 0; i < 4; ++i)
          acc[qg][ug][i] = fmaf(g, lg[qg][ug][i], acc[qg][ug][i]);
    }
    // pin accumulators into arch VGPRs as well
#pragma unroll
    for (int qg = 0; qg < 4; ++qg)
      asm volatile("" : "+v"(acc[qg][0]), "+v"(acc[qg][1]));

    // reset slot (kk+2)%3 (next used at kk+2; barrier(kk+1) separates)
    const int rs = (kk + 2) % 3;
    if (tid < 32) { statM[rs * 32 + tid] = 0u; statS[rs * 32 + tid] = 0.f; }
  }

#pragma unroll
  for (int qg = 0; qg < 4; ++qg)
#pragma unroll
    for (int ug = 0; ug < 2; ++ug)
#pragma unroll
      for (int i = 0; i < 4; ++i)
        atomicAdd(&vsum[(size_t)(b * 512 + w * 64 + qg * 16 + l4 * 4 + i) * 256 +
                        u0 + ug * 16 + l15],
                  acc[qg][ug][i]);
}

extern "C" void kernel_launch(void* const* d_in, const int* in_sizes, int n_in,
                              void* d_out, int out_size, void* d_ws, size_t ws_size,
                              hipStream_t stream) {
  const float* query = (const float*)d_in[0];
  const float* key   = (const float*)d_in[1];
  const float* value = (const float*)d_in[2];
  const float* Wk    = (const float*)d_in[3];
  const float* Wq    = (const float*)d_in[4];
  const float* Wva   = (const float*)d_in[5];
  const float* Wal   = (const float*)d_in[6];
  const float* Wvo   = (const float*)d_in[7];
  float* ws = (float*)d_ws;

  float* kproj = ws;                        // 262144 f32
  float* vproj = kproj + 262144;
  float* vsum  = vproj + 262144;
  short* qpF   = (short*)(vsum + 262144);   // 262144 bf16, A-frag-major
  short* WalF  = qpF + 262144;              // 65536 bf16, frag-major
  float* out   = (float*)d_out;

  proj3<<<dim3(16, 4, 4), 256, 0, stream>>>(key, value, query, Wk, Wq, Wva, Wal,
                                            kproj, vproj, qpF, WalF, vsum);
  kernelC<<<dim3(32, 8, 2), 512, 0, stream>>>(qpF, kproj, vproj, WalF, vsum);
  gemm_out<<<dim3(16, 4), 256, 0, stream>>>(vsum, Wvo, out);
}

// Round 6
// 191.930 us; speedup vs baseline: 2.3130x; 2.3130x over previous
//
#include <hip/hip_runtime.h>
#include <cstdint>

// B=2, Q=512, K=512, T=256 (fp32 in/out).
// R13: kernelC is EXACTLY R11 (proven 110us: 8 waves x 64q x 32u, shfl stats,
// lg/acc pinned, rcp, launch_bounds(512,2), grid (16,8,2)).
// proj3/gemm_out rebuilt: 32-row tiles (2x4 per thread), global prefetch
// pipelining (load t0+16 under compute of t0), gemm_out split-K (2 halves,
// atomicAdd; out zeroed in proj3 z=3).
//   p = x*exp(x); M = max_q x, S = sum_q |p|; acc += p * g,
//   g = vproj*e^-M / (S*e^-M + 1).

typedef short bf16x8 __attribute__((ext_vector_type(8)));   // 8 bf16 = 4 VGPR
typedef float f32x4  __attribute__((ext_vector_type(4)));   // MFMA C/D frag

__device__ inline float bf2f(short s) {
  return __uint_as_float(((unsigned)(unsigned short)s) << 16);
}
// f32 pair -> packed bf16 (round-half-up), low short = lo
__device__ inline unsigned packrn(float lo, float hi) {
  return __builtin_amdgcn_perm(__float_as_uint(hi) + 0x8000u,
                               __float_as_uint(lo) + 0x8000u, 0x07060302u);
}
// monotone (unsigned) encoding of f32 for atomic max; 0 == "-infinity" sentinel
__device__ inline unsigned encM(float f) {
  unsigned k = (unsigned)__float_as_int(f);
  return (k & 0x80000000u) ? ~k : (k | 0x80000000u);
}
__device__ inline float decM(unsigned k) {
  int i = (k & 0x80000000u) ? (int)(k ^ 0x80000000u) : (int)~k;
  return __int_as_float(i);
}

// GEMM body, 32x64 tile, 256 thr, prefetch-pipelined. W row-major
// (transposed through LDS). Computes c[2][4]: rows m0+ty2+{0,1}, cols
// u0+tx4+{0..3}, over K range [K0,K1).
#define GEMM_BODY32(X, W, K0, K1)                                               \
  __shared__ __align__(16) float As[16][36];                                    \
  __shared__ __align__(16) float Ws[16][68];                                    \
  const int tid = threadIdx.x;                                                  \
  const int tx4 = (tid & 15) * 4;                                               \
  const int ty2 = (tid >> 4) * 2;                                               \
  const int m0 = blockIdx.x * 32, u0 = blockIdx.y * 64;                         \
  const int lmi = tid >> 2, lc4 = (tid & 3) * 4;                                \
  const bool hasA = tid < 128;                                                  \
  float4 xa, wb;                                                                \
  if (hasA) xa = *(const float4*)&(X)[(size_t)(m0 + lmi) * 256 + (K0) + lc4];   \
  wb = *(const float4*)&(W)[(size_t)(u0 + lmi) * 256 + (K0) + lc4];             \
  float c[2][4] = {};                                                           \
  _Pragma("unroll 1")                                                           \
  for (int t0 = (K0); t0 < (K1); t0 += 16) {                                    \
    __syncthreads();                                                            \
    if (hasA) {                                                                 \
      As[lc4 + 0][lmi] = xa.x; As[lc4 + 1][lmi] = xa.y;                         \
      As[lc4 + 2][lmi] = xa.z; As[lc4 + 3][lmi] = xa.w;                         \
    }                                                                           \
    Ws[lc4 + 0][lmi] = wb.x; Ws[lc4 + 1][lmi] = wb.y;                           \
    Ws[lc4 + 2][lmi] = wb.z; Ws[lc4 + 3][lmi] = wb.w;                           \
    __syncthreads();                                                            \
    if (t0 + 16 < (K1)) {                                                       \
      if (hasA) xa = *(const float4*)&(X)[(size_t)(m0 + lmi) * 256 + t0 + 16 + lc4]; \
      wb = *(const float4*)&(W)[(size_t)(u0 + lmi) * 256 + t0 + 16 + lc4];      \
    }                                                                           \
    _Pragma("unroll")                                                           \
    for (int t = 0; t < 16; ++t) {                                              \
      const float2 a = *(const float2*)&As[t][ty2];                             \
      const float4 w = *(const float4*)&Ws[t][tx4];                             \
      c[0][0] += a.x*w.x; c[0][1] += a.x*w.y; c[0][2] += a.x*w.z; c[0][3] += a.x*w.w; \
      c[1][0] += a.y*w.x; c[1][1] += a.y*w.y; c[1][2] += a.y*w.z; c[1][3] += a.y*w.w; \
    }                                                                           \
  }

// Projections + aux. z=0 key->kproj(f32), z=1 value->vproj(f32),
// z=2 query->qpF (bf16 A-frag-major), z=3: WalF build + vsum/out zero.
__global__ __launch_bounds__(256) void proj3(
    const float* __restrict__ key, const float* __restrict__ value,
    const float* __restrict__ query, const float* __restrict__ Wk,
    const float* __restrict__ Wq, const float* __restrict__ Wva,
    const float* __restrict__ Wal, float* __restrict__ kproj,
    float* __restrict__ vproj, short* __restrict__ qpF,
    short* __restrict__ WalF, float* __restrict__ vsum,
    float* __restrict__ outz)
{
  const int z = blockIdx.z;
  if (z == 3) {
    const int p = blockIdx.x * 4 + blockIdx.y;    // 0..127, use 0..63
    if (p >= 64) return;
    const int t256 = threadIdx.x;
    // WalF: frag-major bf16 copy of Wal; 1024 shorts per block
#pragma unroll
    for (int e = 0; e < 4; ++e) {
      const int d = p * 1024 + t256 * 4 + e;
      const int j = d & 7, uu = (d >> 3) & 31, c8g = d >> 8;
      const int ucx = c8g >> 5, cc = c8g & 31;
      const float v = Wal[(ucx * 32 + uu) * 256 + cc * 8 + j];
      WalF[d] = (short)packrn(v, v);
    }
    // vsum + out zero: 4096 floats each per block
    float4* vz = (float4*)(vsum + p * 4096);
    float4* oz = (float4*)(outz + p * 4096);
#pragma unroll
    for (int e = 0; e < 4; ++e) {
      vz[t256 * 4 + e] = make_float4(0.f, 0.f, 0.f, 0.f);
      oz[t256 * 4 + e] = make_float4(0.f, 0.f, 0.f, 0.f);
    }
    return;
  }
  const float* X = (z == 0) ? key : (z == 1) ? value : query;
  const float* W = (z == 0) ? Wk  : (z == 1) ? Wva   : Wq;
  GEMM_BODY32(X, W, 0, 256);
  if (z == 2) {
    const int tbase = u0 + tx4;               // t coordinate
    const int ks = tbase >> 5, l4f = (tbase & 31) >> 3, j0 = tbase & 7;
#pragma unroll
    for (int i = 0; i < 2; ++i) {
      const int m = m0 + ty2 + i;             // global row = b*512 + q
      const int bb = m >> 9, q = m & 511;
      const int g = q >> 4, l15q = q & 15;
      const size_t idx = ((size_t)(((bb * 32 + g) * 8 + ks) * 64) + l4f * 16 + l15q) * 8 + j0;
      uint2 s; s.x = packrn(c[i][0], c[i][1]); s.y = packrn(c[i][2], c[i][3]);
      *(uint2*)&qpF[idx] = s;
    }
  } else {
    float* C = (z == 0) ? kproj : vproj;
#pragma unroll
    for (int i = 0; i < 2; ++i)
      *(float4*)&C[(size_t)(m0 + ty2 + i) * 256 + u0 + tx4] =
          make_float4(c[i][0], c[i][1], c[i][2], c[i][3]);
  }
}

// Final projection: out += vsum x Wvo^T over K half blockIdx.z (split-K).
__global__ __launch_bounds__(256) void gemm_out(
    const float* __restrict__ X, const float* __restrict__ W, float* __restrict__ out)
{
  const int kh = blockIdx.z * 128;
  GEMM_BODY32(X, W, kh, kh + 128);
#pragma unroll
  for (int i = 0; i < 2; ++i)
#pragma unroll
    for (int j = 0; j < 4; ++j)
      atomicAdd(&out[(size_t)(m0 + ty2 + i) * 256 + u0 + tx4 + j], c[i][j]);
}

union Frag { bf16x8 v; unsigned u[4]; };

// ---------------------------------------------------------------------------
// kernelC (EXACT R11): grid (16 kt, 8 uc, 2 b), 512 thr = 8 waves; wave w:
// q in [w*64, w*64+64), full 32-u chunk. qa (64q x 256t bf16 = 128 VGPR)
// pinned. Per k (ONE barrier): MFMA from W2F[k&1]; build W2F[(k+1)&1]; shfl
// stats + l4==0 LDS atomics (slot k%3); barrier; per-lane g (rcp); apply;
// reset slot (k+2)%3. lg/acc pinned to "v" class (no AGPR shuttling).
// ---------------------------------------------------------------------------
__global__ __launch_bounds__(512, 2) void kernelC(
    const short* __restrict__ qpF, const float* __restrict__ kproj,
    const float* __restrict__ vproj, const short* __restrict__ WalF,
    float* __restrict__ vsum)
{
  __shared__ __align__(16) short W2F[2][8192];  // 2 x 16 KB, [c8][u][8]
  __shared__ float vpS[32 * 33];                // vproj tile [kk][u], padded
  __shared__ unsigned statM[96];                // 3 slots x 32 u (encoded max)
  __shared__ float statS[96];                   // 3 slots x 32 u

  const int kt = blockIdx.x, uc = blockIdx.y, b = blockIdx.z;
  const int u0 = uc * 32, k0 = kt * 32;
  const int tid = threadIdx.x;
  const int lane = tid & 63, w = tid >> 6;      // w in [0,8)
  const int l15 = lane & 15, l4 = lane >> 4;
  const int uu = tid & 31, c8 = tid >> 5;       // build mapping: c8 and c8+16

  if (tid < 96) { statM[tid] = 0u; statS[tid] = 0.f; }
  {
    const int kk = tid >> 4, uu2 = (tid & 15) * 2;
    const float2 v2 = *(const float2*)&vproj[(size_t)(b * 512 + k0 + kk) * 256 + u0 + uu2];
    vpS[kk * 33 + uu2] = v2.x; vpS[kk * 33 + uu2 + 1] = v2.y;
  }

  // k-invariant Wal build octets (f32-expanded, 16 VGPR)
  float wl0[8], wl1[8];
  {
    const bf16x8 w0 = *(const bf16x8*)&WalF[((size_t)(uc * 32 + c8) * 32 + uu) * 8];
    const bf16x8 w1 = *(const bf16x8*)&WalF[((size_t)(uc * 32 + c8 + 16) * 32 + uu) * 8];
#pragma unroll
    for (int j = 0; j < 8; ++j) { wl0[j] = bf2f(w0[j]); wl1[j] = bf2f(w1[j]); }
  }

  // persistent A-fragments (128 VGPR), pinned against rematerialization
  const short* qbase = qpF + (size_t)b * 131072;
  Frag qa[4][8];
#pragma unroll
  for (int qg = 0; qg < 4; ++qg)
#pragma unroll
    for (int ks = 0; ks < 8; ++ks) {
      qa[qg][ks].v = *(const bf16x8*)&qbase[(((size_t)(w * 4 + qg) * 8 + ks) * 64 + lane) * 8];
      asm volatile("" : "+v"(qa[qg][ks].u[0]), "+v"(qa[qg][ks].u[1]),
                        "+v"(qa[qg][ks].u[2]), "+v"(qa[qg][ks].u[3]));
    }

  // per-thread constant addresses (hoisted once)
  const int fb = (l4 * 32 + l15) * 8;                               // frag base
  const float* kq = &kproj[(long)(b * 512 + k0) * 256 + c8 * 8];    // kp base

  // prologue: build W2F[0] for k = k0
  {
    const f32x4 a0 = *(const f32x4*)(kq);
    const f32x4 a1 = *(const f32x4*)(kq + 4);
    const f32x4 b0 = *(const f32x4*)(kq + 128);
    const f32x4 b1 = *(const f32x4*)(kq + 132);
    uint4 st;
    st.x = packrn(wl0[0] * a0[0], wl0[1] * a0[1]);
    st.y = packrn(wl0[2] * a0[2], wl0[3] * a0[3]);
    st.z = packrn(wl0[4] * a1[0], wl0[5] * a1[1]);
    st.w = packrn(wl0[6] * a1[2], wl0[7] * a1[3]);
    *(uint4*)&W2F[0][(c8 * 32 + uu) * 8] = st;
    st.x = packrn(wl1[0] * b0[0], wl1[1] * b0[1]);
    st.y = packrn(wl1[2] * b0[2], wl1[3] * b0[3]);
    st.z = packrn(wl1[4] * b1[0], wl1[5] * b1[1]);
    st.w = packrn(wl1[6] * b1[2], wl1[7] * b1[3]);
    *(uint4*)&W2F[0][((c8 + 16) * 32 + uu) * 8] = st;
  }
  __syncthreads();

  const f32x4 z4 = {0.f, 0.f, 0.f, 0.f};
  f32x4 acc[4][2] = {z4, z4, z4, z4, z4, z4, z4, z4};

#pragma unroll 1
  for (int kk = 0; kk < 32; ++kk) {
    const int cs = kk & 1, ss = kk % 3;

    // issue next k's kp loads early (hidden under MFMA)
    f32x4 a0, a1, b0, b1;
    if (kk < 31) {
      const float* kn = kq + (size_t)(kk + 1) * 256;
      a0 = *(const f32x4*)(kn);
      a1 = *(const f32x4*)(kn + 4);
      b0 = *(const f32x4*)(kn + 128);
      b1 = *(const f32x4*)(kn + 132);
    }

    f32x4 lg[4][2] = {z4, z4, z4, z4, z4, z4, z4, z4};
#pragma unroll
    for (int ks = 0; ks < 8; ++ks) {
      const bf16x8 f0 = *(const bf16x8*)&W2F[cs][fb + ks * 1024];
      const bf16x8 f1 = *(const bf16x8*)&W2F[cs][fb + ks * 1024 + 128];
#pragma unroll
      for (int qg = 0; qg < 4; ++qg) {
        lg[qg][0] = __builtin_amdgcn_mfma_f32_16x16x32_bf16(qa[qg][ks].v, f0, lg[qg][0], 0, 0, 0);
        lg[qg][1] = __builtin_amdgcn_mfma_f32_16x16x32_bf16(qa[qg][ks].v, f1, lg[qg][1], 0, 0, 0);
      }
    }
    // pin MFMA results into arch VGPRs (prevent AGPR residency -> shuttles)
#pragma unroll
    for (int qg = 0; qg < 4; ++qg)
      asm volatile("" : "+v"(lg[qg][0]), "+v"(lg[qg][1]));

    // build next slot (write-after-read safe: slot read last at kk-1, barrier between)
    if (kk < 31) {
      uint4 st;
      st.x = packrn(wl0[0] * a0[0], wl0[1] * a0[1]);
      st.y = packrn(wl0[2] * a0[2], wl0[3] * a0[3]);
      st.z = packrn(wl0[4] * a1[0], wl0[5] * a1[1]);
      st.w = packrn(wl0[6] * a1[2], wl0[7] * a1[3]);
      *(uint4*)&W2F[cs ^ 1][(c8 * 32 + uu) * 8] = st;
      st.x = packrn(wl1[0] * b0[0], wl1[1] * b0[1]);
      st.y = packrn(wl1[2] * b0[2], wl1[3] * b0[3]);
      st.z = packrn(wl1[4] * b1[0], wl1[5] * b1[1]);
      st.w = packrn(wl1[6] * b1[2], wl1[7] * b1[3]);
      *(uint4*)&W2F[cs ^ 1][((c8 + 16) * 32 + uu) * 8] = st;
    }

    // stats: M = max x (tree), p = x*exp(x), S = sum|p|; shfl reduce across
    // the 4 lane-groups, then one atomic per u from l4==0 lanes.
    float Mv[2], Sv[2];
#pragma unroll
    for (int ug = 0; ug < 2; ++ug) {
      const float m0q = fmaxf(fmaxf(lg[0][ug][0], lg[0][ug][1]), fmaxf(lg[0][ug][2], lg[0][ug][3]));
      const float m1q = fmaxf(fmaxf(lg[1][ug][0], lg[1][ug][1]), fmaxf(lg[1][ug][2], lg[1][ug][3]));
      const float m2q = fmaxf(fmaxf(lg[2][ug][0], lg[2][ug][1]), fmaxf(lg[2][ug][2], lg[2][ug][3]));
      const float m3q = fmaxf(fmaxf(lg[3][ug][0], lg[3][ug][1]), fmaxf(lg[3][ug][2], lg[3][ug][3]));
      float m = fmaxf(fmaxf(m0q, m1q), fmaxf(m2q, m3q));
      float sq[4];
#pragma unroll
      for (int qg = 0; qg < 4; ++qg) {
        float p0 = lg[qg][ug][0] * __expf(lg[qg][ug][0]);
        float p1 = lg[qg][ug][1] * __expf(lg[qg][ug][1]);
        float p2 = lg[qg][ug][2] * __expf(lg[qg][ug][2]);
        float p3 = lg[qg][ug][3] * __expf(lg[qg][ug][3]);
        lg[qg][ug][0] = p0; lg[qg][ug][1] = p1;
        lg[qg][ug][2] = p2; lg[qg][ug][3] = p3;
        sq[qg] = (fabsf(p0) + fabsf(p1)) + (fabsf(p2) + fabsf(p3));
      }
      float s = (sq[0] + sq[1]) + (sq[2] + sq[3]);
      m = fmaxf(m, __shfl_xor(m, 16));
      m = fmaxf(m, __shfl_xor(m, 32));
      s += __shfl_xor(s, 16);
      s += __shfl_xor(s, 32);
      Mv[ug] = m; Sv[ug] = s;
    }
    if (l4 == 0) {
      atomicMax(&statM[ss * 32 + l15],      encM(Mv[0]));
      atomicMax(&statM[ss * 32 + 16 + l15], encM(Mv[1]));
      atomicAdd(&statS[ss * 32 + l15],      Sv[0]);
      atomicAdd(&statS[ss * 32 + 16 + l15], Sv[1]);
    }
    __syncthreads();

    // per-lane g + apply (rcp: err ~1e-7, proven within tolerance)
#pragma unroll
    for (int ug = 0; ug < 2; ++ug) {
      const int ui = ug * 16 + l15;
      const float M = decM(statM[ss * 32 + ui]);
      const float S = statS[ss * 32 + ui];
      const float em = __expf(-M);
      const float g = vpS[kk * 33 + ui] * em * __builtin_amdgcn_rcpf(fmaf(S, em, 1.0f));
#pragma unroll
      for (int qg = 0; qg < 4; ++qg)
#pragma unroll
        for (int i = 0; i < 4; ++i)
          acc[qg][ug][i] = fmaf(g, lg[qg][ug][i], acc[qg][ug][i]);
    }
    // pin accumulators into arch VGPRs as well
#pragma unroll
    for (int qg = 0; qg < 4; ++qg)
      asm volatile("" : "+v"(acc[qg][0]), "+v"(acc[qg][1]));

    // reset slot (kk+2)%3 (next used at kk+2; barrier(kk+1) separates)
    const int rs = (kk + 2) % 3;
    if (tid < 32) { statM[rs * 32 + tid] = 0u; statS[rs * 32 + tid] = 0.f; }
  }

#pragma unroll
  for (int qg = 0; qg < 4; ++qg)
#pragma unroll
    for (int ug = 0; ug < 2; ++ug)
#pragma unroll
      for (int i = 0; i < 4; ++i)
        atomicAdd(&vsum[(size_t)(b * 512 + w * 64 + qg * 16 + l4 * 4 + i) * 256 +
                        u0 + ug * 16 + l15],
                  acc[qg][ug][i]);
}

extern "C" void kernel_launch(void* const* d_in, const int* in_sizes, int n_in,
                              void* d_out, int out_size, void* d_ws, size_t ws_size,
                              hipStream_t stream) {
  const float* query = (const float*)d_in[0];
  const float* key   = (const float*)d_in[1];
  const float* value = (const float*)d_in[2];
  const float* Wk    = (const float*)d_in[3];
  const float* Wq    = (const float*)d_in[4];
  const float* Wva   = (const float*)d_in[5];
  const float* Wal   = (const float*)d_in[6];
  const float* Wvo   = (const float*)d_in[7];
  float* ws = (float*)d_ws;

  float* kproj = ws;                        // 262144 f32
  float* vproj = kproj + 262144;
  float* vsum  = vproj + 262144;
  short* qpF   = (short*)(vsum + 262144);   // 262144 bf16, A-frag-major
  short* WalF  = qpF + 262144;              // 65536 bf16, frag-major
  float* out   = (float*)d_out;

  proj3<<<dim3(32, 4, 4), 256, 0, stream>>>(key, value, query, Wk, Wq, Wva, Wal,
                                            kproj, vproj, qpF, WalF, vsum, out);
  kernelC<<<dim3(16, 8, 2), 512, 0, stream>>>(qpF, kproj, vproj, WalF, vsum);
  gemm_out<<<dim3(32, 4, 2), 256, 0, stream>>>(vsum, Wvo, out);
}